// Round 1
// baseline (337.609 us; speedup 1.0000x reference)
//
#include <hip/hip_runtime.h>
#include <stdint.h>

// Problem constants: B=8, N=2048, F_in=F_out=512
#define NB 8
#define NN 2048
#define NF 512
#define TOTN (NB * NN)   // 16384 nodes total

typedef unsigned short u16;
typedef short bf16x8 __attribute__((ext_vector_type(8)));
typedef float f32x4 __attribute__((ext_vector_type(4)));

__device__ __forceinline__ u16 f2bf(float x) {
  unsigned u = __float_as_uint(x);
  unsigned r = 0x7FFFu + ((u >> 16) & 1u);
  return (u16)((u + r) >> 16);
}
__device__ __forceinline__ float bf2f(u16 u) {
  return __uint_as_float(((unsigned)u) << 16);
}

__device__ __forceinline__ void gl2lds16(const void* g, void* l) {
  // async global->LDS, 16B per lane; LDS dst = wave-uniform base + lane*16
  __builtin_amdgcn_global_load_lds((const __attribute__((address_space(1))) void*)g,
                                   (__attribute__((address_space(3))) void*)l,
                                   16, 0, 0);
}

// ---------------------------------------------------------------------------
// K1: convert text (8.4M fp32) -> bf16, and W -> W^T bf16 (so GEMM1's A operand
// is K-contiguous). Blocks [0,8192) do text (float4 each), [8192,9216) do W^T.
// ---------------------------------------------------------------------------
__global__ __launch_bounds__(256) void conv_kernel(
    const float* __restrict__ text, const float* __restrict__ W,
    u16* __restrict__ text_bf, u16* __restrict__ Wt) {
  int blk = blockIdx.x;
  if (blk < 8192) {
    int idx = blk * 256 + threadIdx.x;       // float4 index, 2,097,152 total
    float4 v = ((const float4*)text)[idx];
    ushort4 o;
    o.x = f2bf(v.x); o.y = f2bf(v.y); o.z = f2bf(v.z); o.w = f2bf(v.w);
    ((ushort4*)text_bf)[idx] = o;
  } else {
    int t = (blk - 8192) * 256 + threadIdx.x;  // 0..262143
    int o = t >> 9, f = t & 511;
    Wt[o * NF + f] = f2bf(W[f * NF + o]);      // Wt[o][f] = W[f][o]
  }
}

// ---------------------------------------------------------------------------
// GEMM core: C[M][N'] = A[M][K] * Bt[N'][K]^T, bf16 inputs, fp32 accum.
// 128x128 block tile, BK=32, 4 waves each computing 64x64 via 4x4 16x16x32 MFMA.
// MODE 0: GEMM1 epilogue  -> hiddenT bf16 [512][16384], + bias[m]
// MODE 1: GEMM2 epilogue  -> out fp32 [(z*2048+m)][512] * linv[z*2048+m]
// ---------------------------------------------------------------------------
template <int MODE>
__global__ __launch_bounds__(256) void gemm_kernel(
    const u16* __restrict__ A, int lda, size_t aOffPerZ,
    const u16* __restrict__ Bt, int ldb, size_t bOffPerZ,
    int K, const float* __restrict__ vec, void* __restrict__ Cptr) {
  __shared__ u16 Alds[128 * 32];
  __shared__ u16 Blds[128 * 32];

  const int z = blockIdx.z;
  const u16* Ab = A + aOffPerZ * (size_t)z;
  const u16* Bb = Bt + bOffPerZ * (size_t)z;
  const int bn = blockIdx.x, bm = blockIdx.y;
  const int t = threadIdx.x, wave = t >> 6, lane = t & 63;
  const int wm = (wave >> 1) * 64, wn = (wave & 1) * 64;

  f32x4 acc[4][4];
#pragma unroll
  for (int i = 0; i < 4; ++i)
#pragma unroll
    for (int j = 0; j < 4; ++j) acc[i][j] = (f32x4){0.f, 0.f, 0.f, 0.f};

  const int rowA0 = bm * 128, rowB0 = bn * 128;
  const int srow = (lane >> 2);          // staging row within 16-row group
  const int scol = (lane & 3) * 8;       // staging col (8 bf16 = 16B)

  for (int kt = 0; kt < K; kt += 32) {
    // stage A tile [128][32]
#pragma unroll
    for (int q = 0; q < 2; ++q) {
      int r = wave * 32 + q * 16;
      gl2lds16(Ab + (size_t)(rowA0 + r + srow) * lda + (kt + scol),
               &Alds[r * 32]);
    }
    // stage B tile [128][32]
#pragma unroll
    for (int q = 0; q < 2; ++q) {
      int r = wave * 32 + q * 16;
      gl2lds16(Bb + (size_t)(rowB0 + r + srow) * ldb + (kt + scol),
               &Blds[r * 32]);
    }
    __syncthreads();  // drains vmcnt before barrier (compiler-inserted)

    const int fr = lane & 15;            // frag row (m or n)
    const int k0 = (lane >> 4) * 8;      // frag k offset
    bf16x8 af[4], bfr[4];
#pragma unroll
    for (int i = 0; i < 4; ++i)
      af[i] = *(const bf16x8*)&Alds[(wm + i * 16 + fr) * 32 + k0];
#pragma unroll
    for (int j = 0; j < 4; ++j)
      bfr[j] = *(const bf16x8*)&Blds[(wn + j * 16 + fr) * 32 + k0];
#pragma unroll
    for (int i = 0; i < 4; ++i)
#pragma unroll
      for (int j = 0; j < 4; ++j)
        acc[i][j] = __builtin_amdgcn_mfma_f32_16x16x32_bf16(af[i], bfr[j],
                                                            acc[i][j], 0, 0, 0);
    __syncthreads();
  }

  // epilogue: C/D layout col = lane&15, row = (lane>>4)*4 + reg
  const int quad = lane >> 4, ln16 = lane & 15;
  if (MODE == 0) {
    u16* hT = (u16*)Cptr;  // [512][16384]
#pragma unroll
    for (int i = 0; i < 4; ++i) {
      int m0 = bm * 128 + wm + i * 16 + quad * 4;
#pragma unroll
      for (int r = 0; r < 4; ++r) {
        int m = m0 + r;
        float bias = vec[m];
#pragma unroll
        for (int j = 0; j < 4; ++j) {
          int n = bn * 128 + wn + j * 16 + ln16;
          hT[(size_t)m * TOTN + n] = f2bf(acc[i][j][r] + bias);
        }
      }
    }
  } else {
    float* outp = (float*)Cptr;  // [16384][512]
#pragma unroll
    for (int i = 0; i < 4; ++i) {
      int m0 = bm * 128 + wm + i * 16 + quad * 4;
#pragma unroll
      for (int r = 0; r < 4; ++r) {
        int m = m0 + r;
        float sc = vec[z * NN + m];  // 1/l for this row
        size_t base = ((size_t)z * NN + m) * (size_t)NF;
#pragma unroll
        for (int j = 0; j < 4; ++j) {
          int n = bn * 128 + wn + j * 16 + ln16;
          outp[base + n] = acc[i][j][r] * sc;
        }
      }
    }
  }
}

// ---------------------------------------------------------------------------
// K3: per-node scores  s[n] = sum_o hT[o][n]*a_src[o],  d likewise.
// Coalesced column reads of hT (lane-adjacent nodes).
// ---------------------------------------------------------------------------
__global__ __launch_bounds__(256) void sd_kernel(
    const u16* __restrict__ hT, const float* __restrict__ a_src,
    const float* __restrict__ a_dst, float* __restrict__ s,
    float* __restrict__ d) {
  int n = blockIdx.x * 256 + threadIdx.x;
  float as = 0.f, ad = 0.f;
#pragma unroll 8
  for (int o = 0; o < NF; ++o) {
    float h = bf2f(hT[(size_t)o * TOTN + n]);
    as = fmaf(h, a_src[o], as);
    ad = fmaf(h, a_dst[o], ad);
  }
  s[n] = as;
  d[n] = ad;
}

// ---------------------------------------------------------------------------
// K4: P[b,i,j] = adj ? 0 : exp(lrelu(s_i + d_j))  (bf16, unnormalized),
//     linv[b,i] = 1/sum_j P.  No max-subtraction: scores <= ~12, exp fits fp32;
//     masked entries underflow to exactly 0 like the reference.
// One block per (b,i) row; 2 vectorized passes of 4 j per thread.
// ---------------------------------------------------------------------------
__global__ __launch_bounds__(256) void pmat_kernel(
    const int* __restrict__ adj, const float* __restrict__ s,
    const float* __restrict__ d, u16* __restrict__ P,
    float* __restrict__ linv) {
  int row = blockIdx.x;       // b*2048 + i
  int b = row >> 11;
  float si = s[row];
  const int* arow = adj + (size_t)row * NN;
  const float* db = d + b * NN;
  u16* prow = P + (size_t)row * NN;
  int t = threadIdx.x;

  float lsum = 0.f;
#pragma unroll
  for (int c = 0; c < 2; ++c) {
    int j4 = c * 1024 + t * 4;
    int4 a4 = *(const int4*)&arow[j4];
    float4 d4 = *(const float4*)&db[j4];
    float x0 = si + d4.x, x1 = si + d4.y, x2 = si + d4.z, x3 = si + d4.w;
    x0 = fmaxf(x0, 0.2f * x0); x1 = fmaxf(x1, 0.2f * x1);
    x2 = fmaxf(x2, 0.2f * x2); x3 = fmaxf(x3, 0.2f * x3);
    float p0 = a4.x ? 0.f : __expf(x0);
    float p1 = a4.y ? 0.f : __expf(x1);
    float p2 = a4.z ? 0.f : __expf(x2);
    float p3 = a4.w ? 0.f : __expf(x3);
    lsum += (p0 + p1) + (p2 + p3);
    ushort4 pk;
    pk.x = f2bf(p0); pk.y = f2bf(p1); pk.z = f2bf(p2); pk.w = f2bf(p3);
    *(ushort4*)&prow[j4] = pk;
  }
  // block reduce (4 waves)
#pragma unroll
  for (int off = 32; off > 0; off >>= 1) lsum += __shfl_down(lsum, off, 64);
  __shared__ float wsum[4];
  int wv = t >> 6, ln = t & 63;
  if (ln == 0) wsum[wv] = lsum;
  __syncthreads();
  if (t == 0) {
    float tot = wsum[0] + wsum[1] + wsum[2] + wsum[3];
    linv[row] = 1.0f / tot;
  }
}

// ---------------------------------------------------------------------------
// launch
// ---------------------------------------------------------------------------
extern "C" void kernel_launch(void* const* d_in, const int* in_sizes, int n_in,
                              void* d_out, int out_size, void* d_ws,
                              size_t ws_size, hipStream_t stream) {
  const float* text  = (const float*)d_in[0];   // [8,2048,512] fp32
  const int*   adj   = (const int*)d_in[1];     // [8,2048,2048] int32
  const float* W     = (const float*)d_in[2];   // [512,512] fp32
  const float* bias  = (const float*)d_in[3];   // [512] fp32 (zeros)
  const float* a_src = (const float*)d_in[4];   // [512] fp32
  const float* a_dst = (const float*)d_in[5];   // [512] fp32
  float* out = (float*)d_out;                   // [8,2048,512] fp32

  // ws layout (bytes), total ~101.4 MB
  char* ws = (char*)d_ws;
  u16*   text_bf = (u16*)(ws + 0);                      // 16,777,216
  u16*   Wt      = (u16*)(ws + 16777216);               //    524,288
  u16*   hT      = (u16*)(ws + 17301504);               // 16,777,216  [512][16384]
  float* s       = (float*)(ws + 34078720);             //     65,536
  float* d       = (float*)(ws + 34144256);             //     65,536
  float* linv    = (float*)(ws + 34209792);             //     65,536
  u16*   P       = (u16*)(ws + 34275328);               // 67,108,864  [16384][2048]

  // K1: convert
  conv_kernel<<<9216, 256, 0, stream>>>(text, W, text_bf, Wt);

  // K2: hiddenT[o][node] = sum_f Wt[o][f] * text_bf[node][f]  (+bias)
  // M=512 (o-tiles: grid.y=4), N'=16384 (node-tiles: grid.x=128), K=512
  gemm_kernel<0><<<dim3(128, 4, 1), 256, 0, stream>>>(
      Wt, NF, 0, text_bf, NF, 0, NF, bias, (void*)hT);

  // K3: per-node src/dst scores
  sd_kernel<<<TOTN / 256, 256, 0, stream>>>(hT, a_src, a_dst, s, d);

  // K4: unnormalized exp-scores P + 1/rowsum
  pmat_kernel<<<TOTN, 256, 0, stream>>>(adj, s, d, P, linv);

  // K5: out[b,i,o] = linv[b,i] * sum_j P[b,i,j] * hiddenT[o][b*2048+j]
  // per batch z: M=2048 (grid.y=16), N'=512 (grid.x=4), K=2048
  gemm_kernel<1><<<dim3(4, 16, NB), 256, 0, stream>>>(
      P, NN, (size_t)NN * NN, hT, TOTN, (size_t)NN, NN, linv, (void*)out);
}